// Round 1
// baseline (375.711 us; speedup 1.0000x reference)
//
#include <hip/hip_runtime.h>

// Problem constants (from reference)
#define BATCH 16384
#define LSEQ  50
#define DIN   20
#define CHN   16
#define HID   6

__device__ __forceinline__ float frcp(float x){ return __builtin_amdgcn_rcpf(x); }
__device__ __forceinline__ float fsig(float x){ return frcp(1.0f + __expf(-x)); }
__device__ __forceinline__ float ftanh(float x){ float t = __expf(2.0f*x); return (t - 1.0f) * frcp(t + 1.0f); }
__device__ __forceinline__ float lrelu(float v){ return v > 0.0f ? v : 0.1f*v; }

// Per-wave LDS slab layout (floats):
//  [0,800)    sAT  : attn[l*16+c]
//  [800,1600) sXE  : xe flat (l*16+c)  -- reused after conv phase:
//     [800,1200)  sWX : (Zinv[j]*x4[j,h]) padded [50][8]
//     [1200,1500) sY  : y0 flat (i*6+h)
//  [1600,2504) sGI  : gi[l*18+g]
//  [2504,2808) sX4  : x4 flat (l*6+h)
//  [2808,3208) sX4P : x4 padded [50][8] (16B-aligned rows)
//  [3208,3264) sFE  : feat[54]
constexpr int SLAB = 3264;

__global__ __launch_bounds__(256, 3) void fused_kernel(
    const float* __restrict__ x,
    const float* __restrict__ we_w, const float* __restrict__ we_b,
    const float* __restrict__ attn_w, const float* __restrict__ attn_b,
    const float* __restrict__ c1w, const float* __restrict__ c1b,
    const float* __restrict__ c2w, const float* __restrict__ c2b,
    const float* __restrict__ c3w, const float* __restrict__ c3b,
    const float* __restrict__ wih, const float* __restrict__ whh,
    const float* __restrict__ bih, const float* __restrict__ bhh,
    const float* __restrict__ fc3w, const float* __restrict__ fc3b,
    float* __restrict__ out)
{
  __shared__ __align__(16) float smem[4 * SLAB];
  const int tid  = threadIdx.x;
  const int wave = tid >> 6;
  const int lane = tid & 63;
  const int b    = blockIdx.x * 4 + wave;

  float* S    = smem + wave * SLAB;
  float* sAT  = S;
  float* sXE  = S + 800;
  float* sWX  = S + 800;   // alias of sXE (valid after conv phase)
  float* sY   = S + 1200;  // alias of sXE[400..700)
  float* sGI  = S + 1600;
  float* sX4  = S + 2504;
  float* sX4P = S + 2808;
  float* sFE  = S + 3208;

  const float* xb = x + (size_t)b * (LSEQ * DIN);
  const int c = lane & 15;       // fixed output channel per lane (64 % 16 == 0)
  const int lbase = lane >> 4;   // fixed l residue per lane

  // ---- Phase 1: xe[l,c] = x[l,:] @ we_w[c,:] + we_b[c] ----
  {
    float wc[DIN];
    #pragma unroll
    for (int d = 0; d < DIN; ++d) wc[d] = we_w[c * DIN + d];
    const float bias = we_b[c];
    for (int k = 0; k < 13; ++k) {
      int l = lbase + 4 * k;
      if (l < LSEQ) {
        const float* xr = xb + l * DIN;
        float acc = bias;
        #pragma unroll
        for (int d = 0; d < DIN; ++d) acc = fmaf(xr[d], wc[d], acc);
        sXE[l * CHN + c] = acc;  // flat index == l*16+c
      }
    }
  }
  __syncthreads();

  // ---- Phase 2: attn[l2,c] = tanh( sum_c' attn_w[c,c'] * xe_flat[c'*50+l2] + attn_b[c] ) ----
  {
    float aw[CHN];
    #pragma unroll
    for (int cc = 0; cc < CHN; ++cc) aw[cc] = attn_w[c * CHN + cc];
    const float ab = attn_b[c];
    for (int k = 0; k < 13; ++k) {
      int l2 = lbase + 4 * k;
      if (l2 < LSEQ) {
        float acc = ab;
        #pragma unroll
        for (int cc = 0; cc < CHN; ++cc) acc = fmaf(sXE[cc * LSEQ + l2], aw[cc], acc);
        sAT[l2 * CHN + c] = ftanh(acc);
      }
    }
  }

  // ---- Phase 3: gi[l,g] = xe[l,:] @ wih[g,:] + bih[g]  (stride 18) ----
  for (int p = lane; p < LSEQ * 18; p += 64) {
    int l = p / 18;
    int g = p - l * 18;
    float acc = bih[g];
    const float* wr = wih + g * CHN;
    const float* xe = sXE + l * CHN;
    #pragma unroll
    for (int cc = 0; cc < CHN; ++cc) acc = fmaf(xe[cc], wr[cc], acc);
    sGI[p] = acc;
  }
  __syncthreads();

  // ---- Phase 4: GRU (serial over 50 steps; h replicated across lanes) ----
  {
    const int g18 = (lane < 18) ? lane : 0;
    float wh[HID];
    #pragma unroll
    for (int k = 0; k < HID; ++k) wh[k] = whh[g18 * HID + k];
    const float bh = bhh[g18];
    const int m6 = lane % 6;
    float hh[HID];
    #pragma unroll
    for (int k = 0; k < HID; ++k) hh[k] = 0.0f;
    float hm = 0.0f;  // this lane's h[m6]
    for (int l = 0; l < LSEQ; ++l) {
      float gh = bh;
      #pragma unroll
      for (int k = 0; k < HID; ++k) gh = fmaf(wh[k], hh[k], gh);  // lane g<18: gh[g]
      float ghr = __shfl(gh, m6);
      float ghz = __shfl(gh, m6 + 6);
      float ghn = __shfl(gh, m6 + 12);
      const float* gl = sGI + l * 18;
      float ir = gl[m6], iz = gl[m6 + 6], in_ = gl[m6 + 12];
      float r = fsig(ir + ghr);
      float z = fsig(iz + ghz);
      float n = ftanh(in_ + r * ghn);
      float hn = (1.0f - z) * n + z * hm;
      hm = hn;
      #pragma unroll
      for (int k = 0; k < HID; ++k) hh[k] = __shfl(hn, k);  // lanes 0..5 hold h[0..5]
      if (lane < HID) { sX4[l * HID + lane] = hn; sX4P[l * 8 + lane] = hn; }
    }
  }
  __syncthreads();

  // ---- Phase 5: convs (k=1,3,5, pads 0,1,2) fused with attn1 reduction -> x_cnn[48] ----
  {
    const int o = c;
    const int seg = lane >> 4;
    const int L0 = (seg < 2) ? seg * 13 : 26 + (seg - 2) * 12;
    const int NL = (seg < 2) ? 13 : 12;
    float z1[13], z2[13], z3[13];
    #pragma unroll
    for (int u = 0; u < 13; ++u) { z1[u] = 0.0f; z2[u] = 0.0f; z3[u] = 0.0f; }
    for (int i = 0; i < CHN; ++i) {
      const float w1 = c1w[o * CHN + i];
      float w2a[3], w3a[5];
      #pragma unroll
      for (int t = 0; t < 3; ++t) w2a[t] = c2w[(o * CHN + i) * 3 + t];
      #pragma unroll
      for (int t = 0; t < 5; ++t) w3a[t] = c3w[(o * CHN + i) * 5 + t];
      float xv[17];
      #pragma unroll
      for (int mm = 0; mm < 17; ++mm) {
        int m = L0 - 2 + mm;
        xv[mm] = (m >= 0 && m < LSEQ) ? sXE[i * LSEQ + m] : 0.0f;  // xr[i,m]
      }
      #pragma unroll
      for (int u = 0; u < 13; ++u) {
        z1[u] = fmaf(w1, xv[u + 2], z1[u]);
        z2[u] += fmaf(w2a[0], xv[u + 1], fmaf(w2a[1], xv[u + 2], w2a[2] * xv[u + 3]));
        z3[u] += fmaf(w3a[0], xv[u], fmaf(w3a[1], xv[u + 1],
                 fmaf(w3a[2], xv[u + 2], fmaf(w3a[3], xv[u + 3], w3a[4] * xv[u + 4]))));
      }
    }
    const float b1v = c1b[o], b2v = c2b[o], b3v = c3b[o];
    float a1 = 0.0f, a2 = 0.0f, a3 = 0.0f;
    #pragma unroll
    for (int u = 0; u < 13; ++u) {
      if (u < NL) {
        int l = L0 + u;
        float v1 = lrelu(z1[u] + b1v);
        float v2 = lrelu(z2[u] + b2v);
        float v3 = lrelu(z3[u] + b3v);
        // attn1[j,l] = attn[(j*50+l)/48, ((j*50+l)%48)&15]
        int f1 = o * LSEQ + l;
        int f2 = (CHN + o) * LSEQ + l;
        int f3 = (2 * CHN + o) * LSEQ + l;
        a1 += v1 * sAT[(f1 / 48) * CHN + ((f1 % 48) & 15)];
        a2 += v2 * sAT[(f2 / 48) * CHN + ((f2 % 48) & 15)];
        a3 += v3 * sAT[(f3 / 48) * CHN + ((f3 % 48) & 15)];
      }
    }
    a1 += __shfl_xor(a1, 16); a1 += __shfl_xor(a1, 32);
    a2 += __shfl_xor(a2, 16); a2 += __shfl_xor(a2, 32);
    a3 += __shfl_xor(a3, 16); a3 += __shfl_xor(a3, 32);
    if (lane < CHN) { sFE[o] = a1; sFE[CHN + o] = a2; sFE[2 * CHN + o] = a3; }
  }
  __syncthreads();

  // ---- Phase 6a: column normalizers Z[j] = sum_i exp(s[i,j]); stage WX[j,h] = x4[j,h]/Z[j] ----
  if (lane < LSEQ) {
    const int j = lane;
    float colj[HID];
    #pragma unroll
    for (int h = 0; h < HID; ++h) colj[h] = sX4[h * LSEQ + j];  // x4r[h,j] (reshape view)
    float zs = 0.0f;
    for (int i = 0; i < LSEQ; ++i) {
      const float4 r0 = *(const float4*)(sX4P + i * 8);
      const float2 r1 = *(const float2*)(sX4P + i * 8 + 4);
      float s = r0.x * colj[0] + r0.y * colj[1] + r0.z * colj[2] +
                r0.w * colj[3] + r1.x * colj[4] + r1.y * colj[5];
      zs += __expf(s * (1.0f / 6.0f));
    }
    const float zinv = frcp(zs);
    #pragma unroll
    for (int h = 0; h < HID; ++h) sWX[j * 8 + h] = zinv * sX4[j * HID + h];
  }
  __syncthreads();

  // ---- Phase 6b: y0[i,h] = sum_j exp(s[i,j]) * WX[j,h] ----
  if (lane < LSEQ) {
    const int i = lane;
    float rowi[HID];
    {
      const float4 q0 = *(const float4*)(sX4P + i * 8);
      const float2 q1 = *(const float2*)(sX4P + i * 8 + 4);
      rowi[0] = q0.x; rowi[1] = q0.y; rowi[2] = q0.z;
      rowi[3] = q0.w; rowi[4] = q1.x; rowi[5] = q1.y;
    }
    float ya[HID];
    #pragma unroll
    for (int h = 0; h < HID; ++h) ya[h] = 0.0f;
    for (int j = 0; j < LSEQ; ++j) {
      float s = 0.0f;
      #pragma unroll
      for (int h = 0; h < HID; ++h) s = fmaf(rowi[h], sX4[h * LSEQ + j], s);
      const float e = __expf(s * (1.0f / 6.0f));
      const float4 w0 = *(const float4*)(sWX + j * 8);
      const float2 w1 = *(const float2*)(sWX + j * 8 + 4);
      ya[0] = fmaf(e, w0.x, ya[0]);
      ya[1] = fmaf(e, w0.y, ya[1]);
      ya[2] = fmaf(e, w0.z, ya[2]);
      ya[3] = fmaf(e, w0.w, ya[3]);
      ya[4] = fmaf(e, w1.x, ya[4]);
      ya[5] = fmaf(e, w1.y, ya[5]);
    }
    #pragma unroll
    for (int h = 0; h < HID; ++h) sY[i * HID + h] = ya[h];
  }
  __syncthreads();

  // ---- Phase 7: x_gru[g] = sum of y0_flat[50g .. 50g+49] (reshape+sum axis=2) ----
  if (lane < HID) {
    float s = 0.0f;
    for (int m = 0; m < LSEQ; ++m) s += sY[lane * LSEQ + m];
    sFE[48 + lane] = s;
  }
  __syncthreads();

  // ---- Phase 8: out[b,:] = fc3_w @ feat + fc3_b ----
  if (lane < 2) {
    float acc = fc3b[lane];
    const float* wr = fc3w + lane * 54;
    #pragma unroll
    for (int k = 0; k < 54; ++k) acc = fmaf(wr[k], sFE[k], acc);
    out[(size_t)b * 2 + lane] = acc;
  }
}

extern "C" void kernel_launch(void* const* d_in, const int* in_sizes, int n_in,
                              void* d_out, int out_size, void* d_ws, size_t ws_size,
                              hipStream_t stream) {
  (void)in_sizes; (void)n_in; (void)d_ws; (void)ws_size; (void)out_size;
  fused_kernel<<<BATCH / 4, 256, 0, stream>>>(
      (const float*)d_in[0],
      (const float*)d_in[1],  (const float*)d_in[2],
      (const float*)d_in[3],  (const float*)d_in[4],
      (const float*)d_in[5],  (const float*)d_in[6],
      (const float*)d_in[7],  (const float*)d_in[8],
      (const float*)d_in[9],  (const float*)d_in[10],
      (const float*)d_in[11], (const float*)d_in[12],
      (const float*)d_in[13], (const float*)d_in[14],
      (const float*)d_in[15], (const float*)d_in[16],
      (float*)d_out);
}

// Round 2
// 309.844 us; speedup vs baseline: 1.2126x; 1.2126x over previous
//
#include <hip/hip_runtime.h>

#define BATCH 16384
#define LSEQ  50
#define DIN   20
#define CHN   16
#define HID   6

__device__ __forceinline__ float frcp(float x){ return __builtin_amdgcn_rcpf(x); }
__device__ __forceinline__ float fsig(float x){ return frcp(1.0f + __expf(-x)); }
__device__ __forceinline__ float ftanh(float x){ float t = __expf(2.0f*x); return (t - 1.0f) * frcp(t + 1.0f); }
__device__ __forceinline__ float lrelu(float v){ return v > 0.0f ? v : 0.1f*v; }

// Per-wave LDS slab (floats), SLAB = 2560 -> 10240 B/wave, 40960 B/block = 4 blocks/CU.
//  [0,800)    sXE : xe flat (l*16+c). ph1 w, ph2/ph5 r. After ph5: sY at [400,700).
//  [800,1800) R1  : gi rows [50][20] (ph1 w, ph4 r) -> sAT [50][16] (ph4.5 w, ph5 r)
//                   -> sC [50][16] rows {T[0..5], pad, WX[8..13]} (ph6).
//  [1800,2104) sX4 : x4 flat (l*6+h). GRU w, ph6a col reads.
//  [2104,2504) sX4P: x4 padded [50][8]. GRU w, ph6 row reads.
//  [2504,2560) sFE : feat[54].
constexpr int SLAB = 2560;

__global__ __launch_bounds__(256, 4) void fused_kernel(
    const float* __restrict__ x,
    const float* __restrict__ we_w, const float* __restrict__ we_b,
    const float* __restrict__ attn_w, const float* __restrict__ attn_b,
    const float* __restrict__ c1w, const float* __restrict__ c1b,
    const float* __restrict__ c2w, const float* __restrict__ c2b,
    const float* __restrict__ c3w, const float* __restrict__ c3b,
    const float* __restrict__ wih, const float* __restrict__ whh,
    const float* __restrict__ bih, const float* __restrict__ bhh,
    const float* __restrict__ fc3w, const float* __restrict__ fc3b,
    float* __restrict__ out)
{
  __shared__ __align__(16) float smem[4 * SLAB];
  const int tid  = threadIdx.x;
  const int wave = tid >> 6;
  const int lane = tid & 63;
  const int b    = blockIdx.x * 4 + wave;

  float* S    = smem + wave * SLAB;
  float* sXE  = S;
  float* sY   = S + 400;   // alias: valid after ph5
  float* R1   = S + 800;   // gi (stride 20) -> sAT -> sC
  float* sX4  = S + 1800;
  float* sX4P = S + 2104;
  float* sFE  = S + 2504;

  const float* xb = x + (size_t)b * (LSEQ * DIN);

  // ---- Phase 1+3: lane l computes xe[l][0..15] and gi[l][0..17] ----
  if (lane < LSEQ) {
    float xv[DIN];
    const float4* xr = (const float4*)(xb + lane * DIN);
    #pragma unroll
    for (int q = 0; q < 5; ++q) {
      float4 v = xr[q];
      xv[4*q] = v.x; xv[4*q+1] = v.y; xv[4*q+2] = v.z; xv[4*q+3] = v.w;
    }
    float xe[CHN];
    #pragma unroll
    for (int c = 0; c < CHN; ++c) {
      float a = we_b[c];
      #pragma unroll
      for (int d = 0; d < DIN; ++d) a = fmaf(xv[d], we_w[c * DIN + d], a);
      xe[c] = a;
    }
    float4* xd = (float4*)(sXE + lane * CHN);
    xd[0] = make_float4(xe[0], xe[1], xe[2], xe[3]);
    xd[1] = make_float4(xe[4], xe[5], xe[6], xe[7]);
    xd[2] = make_float4(xe[8], xe[9], xe[10], xe[11]);
    xd[3] = make_float4(xe[12], xe[13], xe[14], xe[15]);
    float gi[18];
    #pragma unroll
    for (int g = 0; g < 18; ++g) {
      float a = bih[g];
      #pragma unroll
      for (int cc = 0; cc < CHN; ++cc) a = fmaf(xe[cc], wih[g * CHN + cc], a);
      gi[g] = a;
    }
    float4* gd = (float4*)(R1 + lane * 20);
    gd[0] = make_float4(gi[0], gi[1], gi[2], gi[3]);
    gd[1] = make_float4(gi[4], gi[5], gi[6], gi[7]);
    gd[2] = make_float4(gi[8], gi[9], gi[10], gi[11]);
    gd[3] = make_float4(gi[12], gi[13], gi[14], gi[15]);
    *(float2*)(R1 + lane * 20 + 16) = make_float2(gi[16], gi[17]);
  }
  __syncthreads();

  // ---- Phase 4: GRU (serial over 50 steps; h replicated via shuffles) ----
  {
    const int g18 = (lane < 18) ? lane : 0;
    float wh[HID];
    #pragma unroll
    for (int k = 0; k < HID; ++k) wh[k] = whh[g18 * HID + k];
    const float bh = bhh[g18];
    const int m6 = lane % 6;
    float hh[HID];
    #pragma unroll
    for (int k = 0; k < HID; ++k) hh[k] = 0.0f;
    float hm = 0.0f;
    for (int l = 0; l < LSEQ; ++l) {
      float gh = bh;
      #pragma unroll
      for (int k = 0; k < HID; ++k) gh = fmaf(wh[k], hh[k], gh);
      float ghr = __shfl(gh, m6);
      float ghz = __shfl(gh, m6 + 6);
      float ghn = __shfl(gh, m6 + 12);
      const float* gl = R1 + l * 20;
      float r  = fsig(gl[m6] + ghr);
      float z  = fsig(gl[m6 + 6] + ghz);
      float n  = ftanh(gl[m6 + 12] + r * ghn);
      float hn = fmaf(z, hm - n, n);       // (1-z)*n + z*h
      hm = hn;
      #pragma unroll
      for (int k = 0; k < HID; ++k) hh[k] = __shfl(hn, k);
      if (lane < HID) { sX4[l * HID + lane] = hn; sX4P[l * 8 + lane] = hn; }
    }
  }
  __syncthreads();

  // ---- Phase 2 (moved after GRU): attn row per lane; write sAT over dead gi ----
  if (lane < LSEQ) {
    float a[CHN];
    #pragma unroll
    for (int cc = 0; cc < CHN; ++cc) a[cc] = sXE[cc * LSEQ + lane];  // xt[l2][cc]
    float o[CHN];
    #pragma unroll
    for (int c = 0; c < CHN; ++c) {
      float acc = attn_b[c];
      #pragma unroll
      for (int cc = 0; cc < CHN; ++cc) acc = fmaf(a[cc], attn_w[c * CHN + cc], acc);
      o[c] = ftanh(acc);
    }
    float4* ad = (float4*)(R1 + lane * CHN);   // sAT[l2][c]
    ad[0] = make_float4(o[0], o[1], o[2], o[3]);
    ad[1] = make_float4(o[4], o[5], o[6], o[7]);
    ad[2] = make_float4(o[8], o[9], o[10], o[11]);
    ad[3] = make_float4(o[12], o[13], o[14], o[15]);
  }
  __syncthreads();

  // ---- Phase 5: convs fused with attn1 reduction -> x_cnn[48] ----
  {
    float* sAT = R1;
    const int o = lane & 15;
    const int seg = lane >> 4;
    const int L0 = (seg < 2) ? seg * 13 : 26 + (seg - 2) * 12;
    const int NL = (seg < 2) ? 13 : 12;
    int mcl[17];
    #pragma unroll
    for (int mm = 0; mm < 17; ++mm) {
      int m = L0 - 2 + mm;
      mcl[mm] = min(max(m, 0), LSEQ - 1);
    }
    float z1[13], z2[13], z3[13];
    #pragma unroll
    for (int u = 0; u < 13; ++u) { z1[u] = 0.0f; z2[u] = 0.0f; z3[u] = 0.0f; }
    for (int i = 0; i < CHN; ++i) {
      const float w1 = c1w[o * CHN + i];
      float w2a[3], w3a[5];
      #pragma unroll
      for (int t = 0; t < 3; ++t) w2a[t] = c2w[(o * CHN + i) * 3 + t];
      #pragma unroll
      for (int t = 0; t < 5; ++t) w3a[t] = c3w[(o * CHN + i) * 5 + t];
      const float* xrow = sXE + i * LSEQ;
      float xv[17];
      #pragma unroll
      for (int mm = 0; mm < 17; ++mm) {
        float v = xrow[mcl[mm]];
        if (mm < 2 || mm >= 14) {           // only edges can be OOB (compile-time)
          int m = L0 - 2 + mm;
          v = (m == mcl[mm]) ? v : 0.0f;
        }
        xv[mm] = v;
      }
      #pragma unroll
      for (int u = 0; u < 13; ++u) {
        z1[u] = fmaf(w1, xv[u + 2], z1[u]);
        z2[u] = fmaf(w2a[0], xv[u + 1], z2[u]);
        z2[u] = fmaf(w2a[1], xv[u + 2], z2[u]);
        z2[u] = fmaf(w2a[2], xv[u + 3], z2[u]);
        z3[u] = fmaf(w3a[0], xv[u],     z3[u]);
        z3[u] = fmaf(w3a[1], xv[u + 1], z3[u]);
        z3[u] = fmaf(w3a[2], xv[u + 2], z3[u]);
        z3[u] = fmaf(w3a[3], xv[u + 3], z3[u]);
        z3[u] = fmaf(w3a[4], xv[u + 4], z3[u]);
      }
    }
    const float b1v = c1b[o], b2v = c2b[o], b3v = c3b[o];
    float a1 = 0.0f, a2 = 0.0f, a3 = 0.0f;
    #pragma unroll
    for (int u = 0; u < 13; ++u) {
      if (u < NL) {
        int l = L0 + u;
        float v1 = lrelu(z1[u] + b1v);
        float v2 = lrelu(z2[u] + b2v);
        float v3 = lrelu(z3[u] + b3v);
        int f1 = o * LSEQ + l;
        int f2 = (CHN + o) * LSEQ + l;
        int f3 = (2 * CHN + o) * LSEQ + l;
        a1 += v1 * sAT[(f1 / 48) * CHN + ((f1 % 48) & 15)];
        a2 += v2 * sAT[(f2 / 48) * CHN + ((f2 % 48) & 15)];
        a3 += v3 * sAT[(f3 / 48) * CHN + ((f3 % 48) & 15)];
      }
    }
    a1 += __shfl_xor(a1, 16); a1 += __shfl_xor(a1, 32);
    a2 += __shfl_xor(a2, 16); a2 += __shfl_xor(a2, 32);
    a3 += __shfl_xor(a3, 16); a3 += __shfl_xor(a3, 32);
    if (lane < CHN) { sFE[o] = a1; sFE[CHN + o] = a2; sFE[2 * CHN + o] = a3; }
  }
  __syncthreads();

  // ---- Phase 6a: T rows + column normalizers; sC[j] = {T[j][0..5], -, Zinv*x4[j][0..5]} ----
  float* sC = R1;
  if (lane < LSEQ) {
    float colj[HID];
    #pragma unroll
    for (int h = 0; h < HID; ++h) colj[h] = sX4[h * LSEQ + lane];  // x4r[h][j]
    *(float4*)(sC + lane * 16)     = make_float4(colj[0], colj[1], colj[2], colj[3]);
    *(float2*)(sC + lane * 16 + 4) = make_float2(colj[4], colj[5]);
    float zs = 0.0f;
    for (int i = 0; i < LSEQ; ++i) {
      const float4 r0 = *(const float4*)(sX4P + i * 8);
      const float2 r1 = *(const float2*)(sX4P + i * 8 + 4);
      float s = r0.x * colj[0];
      s = fmaf(r0.y, colj[1], s); s = fmaf(r0.z, colj[2], s);
      s = fmaf(r0.w, colj[3], s); s = fmaf(r1.x, colj[4], s);
      s = fmaf(r1.y, colj[5], s);
      zs += __expf(s * (1.0f / 6.0f));
    }
    const float zi = frcp(zs);
    const float4 q0 = *(const float4*)(sX4P + lane * 8);
    const float2 q1 = *(const float2*)(sX4P + lane * 8 + 4);
    *(float4*)(sC + lane * 16 + 8)  = make_float4(zi*q0.x, zi*q0.y, zi*q0.z, zi*q0.w);
    *(float2*)(sC + lane * 16 + 12) = make_float2(zi*q1.x, zi*q1.y);
  }
  __syncthreads();

  // ---- Phase 6b: y0[i][h] = sum_j exp(s[i,j]/6) * WX[j][h] ----
  if (lane < LSEQ) {
    float rowi[HID];
    {
      const float4 q0 = *(const float4*)(sX4P + lane * 8);
      const float2 q1 = *(const float2*)(sX4P + lane * 8 + 4);
      rowi[0] = q0.x; rowi[1] = q0.y; rowi[2] = q0.z;
      rowi[3] = q0.w; rowi[4] = q1.x; rowi[5] = q1.y;
    }
    float ya[HID];
    #pragma unroll
    for (int h = 0; h < HID; ++h) ya[h] = 0.0f;
    for (int j = 0; j < LSEQ; ++j) {
      const float4 t0 = *(const float4*)(sC + j * 16);
      const float2 t1 = *(const float2*)(sC + j * 16 + 4);
      float s = rowi[0] * t0.x;
      s = fmaf(rowi[1], t0.y, s); s = fmaf(rowi[2], t0.z, s);
      s = fmaf(rowi[3], t0.w, s); s = fmaf(rowi[4], t1.x, s);
      s = fmaf(rowi[5], t1.y, s);
      const float e = __expf(s * (1.0f / 6.0f));
      const float4 w0 = *(const float4*)(sC + j * 16 + 8);
      const float2 w1 = *(const float2*)(sC + j * 16 + 12);
      ya[0] = fmaf(e, w0.x, ya[0]);
      ya[1] = fmaf(e, w0.y, ya[1]);
      ya[2] = fmaf(e, w0.z, ya[2]);
      ya[3] = fmaf(e, w0.w, ya[3]);
      ya[4] = fmaf(e, w1.x, ya[4]);
      ya[5] = fmaf(e, w1.y, ya[5]);
    }
    *(float2*)(sY + lane * 6)     = make_float2(ya[0], ya[1]);
    *(float2*)(sY + lane * 6 + 2) = make_float2(ya[2], ya[3]);
    *(float2*)(sY + lane * 6 + 4) = make_float2(ya[4], ya[5]);
  }
  __syncthreads();

  // ---- Phase 7: x_gru[g] = sum of y0_flat[50g .. 50g+49] ----
  if (lane < HID) {
    float s = 0.0f;
    for (int m = 0; m < LSEQ; ++m) s += sY[lane * LSEQ + m];
    sFE[48 + lane] = s;
  }
  __syncthreads();

  // ---- Phase 8: out[b][:] = fc3_w @ feat + fc3_b ----
  if (lane < 2) {
    float acc = fc3b[lane];
    const float* wr = fc3w + lane * 54;
    #pragma unroll
    for (int k = 0; k < 54; ++k) acc = fmaf(wr[k], sFE[k], acc);
    out[(size_t)b * 2 + lane] = acc;
  }
}

extern "C" void kernel_launch(void* const* d_in, const int* in_sizes, int n_in,
                              void* d_out, int out_size, void* d_ws, size_t ws_size,
                              hipStream_t stream) {
  (void)in_sizes; (void)n_in; (void)d_ws; (void)ws_size; (void)out_size;
  fused_kernel<<<BATCH / 4, 256, 0, stream>>>(
      (const float*)d_in[0],
      (const float*)d_in[1],  (const float*)d_in[2],
      (const float*)d_in[3],  (const float*)d_in[4],
      (const float*)d_in[5],  (const float*)d_in[6],
      (const float*)d_in[7],  (const float*)d_in[8],
      (const float*)d_in[9],  (const float*)d_in[10],
      (const float*)d_in[11], (const float*)d_in[12],
      (const float*)d_in[13], (const float*)d_in[14],
      (const float*)d_in[15], (const float*)d_in[16],
      (float*)d_out);
}